// Round 2
// baseline (617.343 us; speedup 1.0000x reference)
//
#include <hip/hip_runtime.h>

#define CC 19
#define NPOS 361
#define NPAD 384
#define DIM 256
#define BB 32
#define TKEY 32
#define NTILES 12

// LDS layout (bytes), TKEY=32:
//   sQ  : 32 x 264 bf16 = 16896   [0)       reused as attn-out in epilogue
//   sK  : 32 x 264 bf16 = 16896   [16896)   reused as proj intermediate
//   sVT : 256 x 40 bf16 = 20480   [33792)
//   sXP : max(sX 32x264=16896, sP 8x32x40=20480) = 20480  [54272)
// total = 74752  (<= 80KB -> 2 blocks/CU)
#define LDS_BYTES 74752

using bf16x8 = __attribute__((ext_vector_type(8))) short;
using floatx4 = __attribute__((ext_vector_type(4))) float;

__device__ __forceinline__ unsigned short f2bf(float f) {
  unsigned u = __builtin_bit_cast(unsigned, f);
  u += 0x7fffu + ((u >> 16) & 1u);
  return (unsigned short)(u >> 16);
}

// one fused conversion kernel: x (zero-padded 361->384 rows) + all weights, f32 -> bf16
// job ranges in float4 units:
//   [0, 786432)            x      -> ws[0)            (32*384*256 shorts)
//   [786432, 1720320)      w_in   -> ws[3145728)      (19*768*256)
//   [1720320, 2031616)     w_out  -> ws[6881280)      (19*256*256)
//   [2031616, 2048000)     w_fuse -> ws[8126464)      (256*256)
__global__ void conv_all_kernel(const float* __restrict__ x,
                                const float* __restrict__ w_in,
                                const float* __restrict__ w_out,
                                const float* __restrict__ w_fuse,
                                unsigned short* __restrict__ ws) {
  const int j = blockIdx.x * 256 + threadIdx.x;
  float4 v = make_float4(0.f, 0.f, 0.f, 0.f);
  unsigned short* dst;
  if (j < 786432) {
    const int row = j >> 6;
    const int off = (j & 63) << 2;
    const int b = row / NPAD;
    const int r = row - b * NPAD;
    if (r < NPOS) v = *(const float4*)&x[(b * NPOS + r) * DIM + off];
    dst = &ws[row * DIM + off];
  } else if (j < 1720320) {
    const int k = j - 786432;
    v = *(const float4*)&w_in[k << 2];
    dst = &ws[3145728 + (k << 2)];
  } else if (j < 2031616) {
    const int k = j - 1720320;
    v = *(const float4*)&w_out[k << 2];
    dst = &ws[6881280 + (k << 2)];
  } else {
    const int k = j - 2031616;
    v = *(const float4*)&w_fuse[k << 2];
    dst = &ws[8126464 + (k << 2)];
  }
  ushort4 o;
  o.x = f2bf(v.x); o.y = f2bf(v.y); o.z = f2bf(v.z); o.w = f2bf(v.w);
  *(ushort4*)dst = o;
}

__launch_bounds__(512, 4)
__global__ void cgca_kernel(const float* __restrict__ xf,
                            const float* __restrict__ b_in,
                            const float* __restrict__ b_out,
                            const float* __restrict__ b_fuse,
                            const unsigned short* __restrict__ xbf,
                            const unsigned short* __restrict__ wibf,
                            const unsigned short* __restrict__ wobf,
                            const unsigned short* __restrict__ wfbf,
                            float* __restrict__ out) {
  // XCD-aware swizzle: same channel's 32 batches contiguous on one XCD.
  const int bid = blockIdx.x;
  const int xcd = bid & 7;
  const int slot = bid >> 3;
  int c, b;
  if (slot < 64) {
    c = ((slot >> 5) << 3) + xcd;   // channels 0..15
    b = slot & 31;
  } else {
    const int widx = ((slot - 64) << 3) + xcd;  // 0..95
    c = 16 + (widx >> 5);           // channels 16..18
    b = widx & 31;
  }

  const int tid = threadIdx.x;
  const int w = tid >> 6;        // wave 0..7 == head index
  const int lane = tid & 63;
  const int quad = lane >> 4;
  const int l16 = lane & 15;

  extern __shared__ char smem[];
  unsigned short* sQ  = (unsigned short*)(smem);
  unsigned short* sK  = (unsigned short*)(smem + 16896);
  unsigned short* sVT = (unsigned short*)(smem + 33792);
  unsigned short* sX  = (unsigned short*)(smem + 54272);
  unsigned short* sP  = (unsigned short*)(smem + 54272) + w * (32 * 40);

  const float scale = 0.17677669529663687f;  // 1/sqrt(32)
  const floatx4 fzero = {0.f, 0.f, 0.f, 0.f};

  // ---------------- Phase 1: Q = xq @ wq^T + bq (scaled) -> sQ bf16 [32][264]
  {
    const int eh0 = w * 32;
#pragma unroll
    for (int mt = 0; mt < 2; ++mt) {
      const int xrow = b * NPAD + c * CC + mt * 16 + l16;  // zero-padded rows
      bf16x8 a8[8];
#pragma unroll
      for (int k = 0; k < 8; ++k)
        a8[k] = *(const bf16x8*)&xbf[xrow * DIM + k * 32 + quad * 8];
#pragma unroll
      for (int nt2 = 0; nt2 < 2; ++nt2) {
        const int e0 = eh0 + nt2 * 16;
        floatx4 acc = fzero;
#pragma unroll
        for (int k = 0; k < 8; ++k) {
          bf16x8 b8 = *(const bf16x8*)&wibf[(c * 768 + e0 + l16) * DIM + k * 32 + quad * 8];
          acc = __builtin_amdgcn_mfma_f32_16x16x32_bf16(a8[k], b8, acc, 0, 0, 0);
        }
        const float bias = b_in[c * 768 + e0 + l16];
#pragma unroll
        for (int r = 0; r < 4; ++r)
          sQ[(mt * 16 + quad * 4 + r) * 264 + e0 + l16] = f2bf((acc[r] + bias) * scale);
      }
    }
  }

  // attention running state (per wave-head; rows q = mt*16 + quad*4 + r)
  floatx4 o_acc[2][2];
  float m_run[2][4], l_run[2][4];
#pragma unroll
  for (int mt = 0; mt < 2; ++mt) {
#pragma unroll
    for (int nt2 = 0; nt2 < 2; ++nt2) o_acc[mt][nt2] = fzero;
#pragma unroll
    for (int r = 0; r < 4; ++r) { m_run[mt][r] = -1e30f; l_run[mt][r] = 0.f; }
  }
  const int eh = w * 32;

  for (int t = 0; t < NTILES; ++t) {
    const int t0 = t * TKEY;
    __syncthreads();  // protect sX(=sP) + sK/sVT reuse from previous tile

    // stage x tile [32][264 padded] bf16
#pragma unroll
    for (int it = 0; it < 2; ++it) {
      const int cc2 = tid + it * 512;
      const int row = cc2 >> 5;
      const int col = (cc2 & 31) * 8;
      *(bf16x8*)&sX[row * 264 + col] = *(const bf16x8*)&xbf[(b * NPAD + t0 + row) * DIM + col];
    }
    __syncthreads();

    // ---------------- KV^T projection: rows e' = w*64..w*64+63 of [wk;wv]
    {
      floatx4 acc[4][2];
#pragma unroll
      for (int m4 = 0; m4 < 4; ++m4)
#pragma unroll
        for (int n4 = 0; n4 < 2; ++n4) acc[m4][n4] = fzero;

      const int wrow0 = c * 768 + 256 + w * 64;
      bf16x8 abuf[2][4];
#pragma unroll
      for (int m4 = 0; m4 < 4; ++m4)
        abuf[0][m4] = *(const bf16x8*)&wibf[(wrow0 + m4 * 16 + l16) * DIM + quad * 8];
#pragma unroll
      for (int k = 0; k < 8; ++k) {
        if (k < 7) {
#pragma unroll
          for (int m4 = 0; m4 < 4; ++m4)
            abuf[(k + 1) & 1][m4] =
                *(const bf16x8*)&wibf[(wrow0 + m4 * 16 + l16) * DIM + (k + 1) * 32 + quad * 8];
        }
        bf16x8 bfr[2];
#pragma unroll
        for (int n4 = 0; n4 < 2; ++n4)
          bfr[n4] = *(const bf16x8*)&sX[(n4 * 16 + l16) * 264 + k * 32 + quad * 8];
#pragma unroll
        for (int m4 = 0; m4 < 4; ++m4)
#pragma unroll
          for (int n4 = 0; n4 < 2; ++n4)
            acc[m4][n4] = __builtin_amdgcn_mfma_f32_16x16x32_bf16(abuf[k & 1][m4], bfr[n4],
                                                                  acc[m4][n4], 0, 0, 0);
      }
      // epilogue: +bias, cvt bf16, store K [key][e] / V^T [e][key]
#pragma unroll
      for (int m4 = 0; m4 < 4; ++m4) {
        const float4 bv = *(const float4*)&b_in[c * 768 + 256 + w * 64 + m4 * 16 + quad * 4];
        const float ba[4] = {bv.x, bv.y, bv.z, bv.w};
#pragma unroll
        for (int n4 = 0; n4 < 2; ++n4) {
          const int key = n4 * 16 + l16;
          if (w < 4) {
            const int e0 = w * 64 + m4 * 16 + quad * 4;
            ushort4 pk;
            pk.x = f2bf(acc[m4][n4][0] + ba[0]);
            pk.y = f2bf(acc[m4][n4][1] + ba[1]);
            pk.z = f2bf(acc[m4][n4][2] + ba[2]);
            pk.w = f2bf(acc[m4][n4][3] + ba[3]);
            *(ushort4*)&sK[key * 264 + e0] = pk;
          } else {
            const int e0 = (w - 4) * 64 + m4 * 16 + quad * 4;
#pragma unroll
            for (int r = 0; r < 4; ++r)
              sVT[(e0 + r) * 40 + key] = f2bf(acc[m4][n4][r] + ba[r]);
          }
        }
      }
    }
    __syncthreads();

    // ---------------- scores + mask + online softmax + P (head = w)
    {
#pragma unroll
      for (int mt = 0; mt < 2; ++mt) {
        const bf16x8 aq = *(const bf16x8*)&sQ[(mt * 16 + l16) * 264 + eh + quad * 8];
        floatx4 sc[2];
#pragma unroll
        for (int n4 = 0; n4 < 2; ++n4) {
          const bf16x8 bk = *(const bf16x8*)&sK[(n4 * 16 + l16) * 264 + eh + quad * 8];
          sc[n4] = __builtin_amdgcn_mfma_f32_16x16x32_bf16(aq, bk, fzero, 0, 0, 0);
        }
        float rowm[4] = {-1e30f, -1e30f, -1e30f, -1e30f};
#pragma unroll
        for (int n4 = 0; n4 < 2; ++n4) {
          const int kabs = t0 + n4 * 16 + l16;
          const unsigned ki = ((unsigned)kabs * 110377u) >> 21;  // kabs/19 for kabs<=383
          const unsigned kj = (unsigned)kabs - ki * 19u;
#pragma unroll
          for (int r = 0; r < 4; ++r) {
            const unsigned j = (unsigned)(mt * 16 + quad * 4 + r);
            const bool ok = (kabs < NPOS) &&
                            (ki == (unsigned)c || kj == (unsigned)c || ki == j || kj == j);
            const float v = ok ? sc[n4][r] : -1e30f;
            sc[n4][r] = v;
            rowm[r] = fmaxf(rowm[r], v);
          }
        }
#pragma unroll
        for (int r = 0; r < 4; ++r) {
#pragma unroll
          for (int m = 1; m < 16; m <<= 1) rowm[r] = fmaxf(rowm[r], __shfl_xor(rowm[r], m));
        }
        float alpha[4];
#pragma unroll
        for (int r = 0; r < 4; ++r) {
          const float mnew = fmaxf(m_run[mt][r], rowm[r]);
          alpha[r] = __expf(m_run[mt][r] - mnew);
          m_run[mt][r] = mnew;
          l_run[mt][r] *= alpha[r];
        }
        float rs[4] = {0.f, 0.f, 0.f, 0.f};
#pragma unroll
        for (int n4 = 0; n4 < 2; ++n4) {
#pragma unroll
          for (int r = 0; r < 4; ++r) {
            const float p = __expf(sc[n4][r] - m_run[mt][r]);
            rs[r] += p;
            sP[(mt * 16 + quad * 4 + r) * 40 + n4 * 16 + l16] = f2bf(p);
          }
        }
#pragma unroll
        for (int r = 0; r < 4; ++r) {
#pragma unroll
          for (int m = 1; m < 16; m <<= 1) rs[r] += __shfl_xor(rs[r], m);
          l_run[mt][r] += rs[r];
        }
#pragma unroll
        for (int nt2 = 0; nt2 < 2; ++nt2)
#pragma unroll
          for (int r = 0; r < 4; ++r) o_acc[mt][nt2][r] *= alpha[r];
      }
    }
    __syncthreads();

    // ---------------- PV: O += P @ V (head = w), single K=32 step
    {
      bf16x8 ap[2], bv8[2];
#pragma unroll
      for (int mt = 0; mt < 2; ++mt)
        ap[mt] = *(const bf16x8*)&sP[(mt * 16 + l16) * 40 + quad * 8];
#pragma unroll
      for (int nt2 = 0; nt2 < 2; ++nt2)
        bv8[nt2] = *(const bf16x8*)&sVT[(eh + nt2 * 16 + l16) * 40 + quad * 8];
#pragma unroll
      for (int mt = 0; mt < 2; ++mt)
#pragma unroll
        for (int nt2 = 0; nt2 < 2; ++nt2)
          o_acc[mt][nt2] =
              __builtin_amdgcn_mfma_f32_16x16x32_bf16(ap[mt], bv8[nt2], o_acc[mt][nt2], 0, 0, 0);
    }
  }  // tile loop

  // ---------------- finalize O -> sQ (as attn-out, bf16)
#pragma unroll
  for (int mt = 0; mt < 2; ++mt) {
    float invl[4];
#pragma unroll
    for (int r = 0; r < 4; ++r) invl[r] = 1.f / l_run[mt][r];
#pragma unroll
    for (int nt2 = 0; nt2 < 2; ++nt2)
#pragma unroll
      for (int r = 0; r < 4; ++r)
        sQ[(mt * 16 + quad * 4 + r) * 264 + eh + nt2 * 16 + l16] = f2bf(o_acc[mt][nt2][r] * invl[r]);
  }
  __syncthreads();

  // ---------------- GEMM1: proj = AO @ w_out^T + b_out -> sK (bf16)
#pragma unroll
  for (int mt = 0; mt < 2; ++mt) {
    bf16x8 a8[8];
#pragma unroll
    for (int k = 0; k < 8; ++k)
      a8[k] = *(const bf16x8*)&sQ[(mt * 16 + l16) * 264 + k * 32 + quad * 8];
#pragma unroll
    for (int nt2 = 0; nt2 < 2; ++nt2) {
      const int e0 = w * 32 + nt2 * 16;
      floatx4 acc = fzero;
#pragma unroll
      for (int k = 0; k < 8; ++k) {
        bf16x8 b8 = *(const bf16x8*)&wobf[(c * 256 + e0 + l16) * DIM + k * 32 + quad * 8];
        acc = __builtin_amdgcn_mfma_f32_16x16x32_bf16(a8[k], b8, acc, 0, 0, 0);
      }
      const float bias = b_out[c * 256 + e0 + l16];
#pragma unroll
      for (int r = 0; r < 4; ++r)
        sK[(mt * 16 + quad * 4 + r) * 264 + e0 + l16] = f2bf(acc[r] + bias);
    }
  }
  __syncthreads();

  // ---------------- GEMM2: out = proj @ w_fuse^T + b_fuse + x
#pragma unroll
  for (int mt = 0; mt < 2; ++mt) {
    bf16x8 a8[8];
#pragma unroll
    for (int k = 0; k < 8; ++k)
      a8[k] = *(const bf16x8*)&sK[(mt * 16 + l16) * 264 + k * 32 + quad * 8];
#pragma unroll
    for (int nt2 = 0; nt2 < 2; ++nt2) {
      const int e0 = w * 32 + nt2 * 16;
      floatx4 acc = fzero;
#pragma unroll
      for (int k = 0; k < 8; ++k) {
        bf16x8 b8 = *(const bf16x8*)&wfbf[(e0 + l16) * DIM + k * 32 + quad * 8];
        acc = __builtin_amdgcn_mfma_f32_16x16x32_bf16(a8[k], b8, acc, 0, 0, 0);
      }
      const float bfu = b_fuse[e0 + l16];
#pragma unroll
      for (int r = 0; r < 4; ++r) {
        const int row = mt * 16 + quad * 4 + r;
        if (row < CC) {
          const int gp = (b * NPOS + c * CC + row) * DIM + e0 + l16;
          out[gp] = acc[r] + bfu + xf[gp];
        }
      }
    }
  }
}

extern "C" void kernel_launch(void* const* d_in, const int* in_sizes, int n_in,
                              void* d_out, int out_size, void* d_ws, size_t ws_size,
                              hipStream_t stream) {
  const float* x      = (const float*)d_in[0];
  const float* w_in   = (const float*)d_in[1];
  const float* b_in   = (const float*)d_in[2];
  const float* w_out  = (const float*)d_in[3];
  const float* b_out  = (const float*)d_in[4];
  const float* w_fuse = (const float*)d_in[5];
  const float* b_fuse = (const float*)d_in[6];
  float* out = (float*)d_out;

  if (ws_size < (size_t)16384000) return;  // need 15.6 MB of bf16 scratch

  unsigned short* ws = (unsigned short*)d_ws;
  unsigned short* x_bf  = ws;              // 32*384*256   = 3,145,728
  unsigned short* wi_bf = ws + 3145728;    // 19*768*256   = 3,735,552
  unsigned short* wo_bf = ws + 6881280;    // 19*256*256   = 1,245,184
  unsigned short* wf_bf = ws + 8126464;    // 256*256      = 65,536

  conv_all_kernel<<<8000, 256, 0, stream>>>(x, w_in, w_out, w_fuse, ws);

  (void)hipFuncSetAttribute((const void*)cgca_kernel,
                            hipFuncAttributeMaxDynamicSharedMemorySize, LDS_BYTES);
  cgca_kernel<<<608, 512, LDS_BYTES, stream>>>(x, b_in, b_out, b_fuse, x_bf, wi_bf,
                                               wo_bf, wf_bf, out);
}

// Round 3
// 390.615 us; speedup vs baseline: 1.5804x; 1.5804x over previous
//
#include <hip/hip_runtime.h>

#define CC 19
#define NPOS 361
#define NPAD 384
#define DIM 256
#define BB 32
#define TKEY 32
#define NTILES 12

// LDS layout (bytes), TKEY=32:
//   sQ  : 32 x 264 bf16 = 16896   [0)       reused as attn-out in epilogue
//   sK  : 32 x 264 bf16 = 16896   [16896)   reused as proj intermediate
//   sVT : 256 x 40 bf16 = 20480   [33792)
//   sXP : max(sX 32x264=16896, sP 8x32x40=20480) = 20480  [54272)
// total = 74752  (<= 80KB -> 2 blocks/CU from LDS)
#define LDS_BYTES 74752

using bf16x8 = __attribute__((ext_vector_type(8))) short;
using floatx4 = __attribute__((ext_vector_type(4))) float;

__device__ __forceinline__ unsigned short f2bf(float f) {
  unsigned u = __builtin_bit_cast(unsigned, f);
  u += 0x7fffu + ((u >> 16) & 1u);
  return (unsigned short)(u >> 16);
}

// one fused conversion kernel: x (zero-padded 361->384 rows) + all weights, f32 -> bf16
__global__ void conv_all_kernel(const float* __restrict__ x,
                                const float* __restrict__ w_in,
                                const float* __restrict__ w_out,
                                const float* __restrict__ w_fuse,
                                unsigned short* __restrict__ ws) {
  const int j = blockIdx.x * 256 + threadIdx.x;
  float4 v = make_float4(0.f, 0.f, 0.f, 0.f);
  unsigned short* dst;
  if (j < 786432) {
    const int row = j >> 6;
    const int off = (j & 63) << 2;
    const int b = row / NPAD;
    const int r = row - b * NPAD;
    if (r < NPOS) v = *(const float4*)&x[(b * NPOS + r) * DIM + off];
    dst = &ws[row * DIM + off];
  } else if (j < 1720320) {
    const int k = j - 786432;
    v = *(const float4*)&w_in[k << 2];
    dst = &ws[3145728 + (k << 2)];
  } else if (j < 2031616) {
    const int k = j - 1720320;
    v = *(const float4*)&w_out[k << 2];
    dst = &ws[6881280 + (k << 2)];
  } else {
    const int k = j - 2031616;
    v = *(const float4*)&w_fuse[k << 2];
    dst = &ws[8126464 + (k << 2)];
  }
  ushort4 o;
  o.x = f2bf(v.x); o.y = f2bf(v.y); o.z = f2bf(v.z); o.w = f2bf(v.w);
  *(ushort4*)dst = o;
}

// launch_bounds (512,2): VGPR cap 256 -> compiler settles ~128, no spills (R2's
// (512,4) forced 64 VGPRs -> scratch spills -> FETCH_SIZE 3x, dur +60%).
// Occupancy 2 blocks/CU comes from LDS (74.75KB of 160KB), not the bound.
__launch_bounds__(512, 2)
__global__ void cgca_kernel(const float* __restrict__ xf,
                            const float* __restrict__ b_in,
                            const float* __restrict__ b_out,
                            const float* __restrict__ b_fuse,
                            const unsigned short* __restrict__ xbf,
                            const unsigned short* __restrict__ wibf,
                            const unsigned short* __restrict__ wobf,
                            const unsigned short* __restrict__ wfbf,
                            float* __restrict__ out) {
  // XCD-aware swizzle: same channel's 32 batches contiguous on one XCD.
  const int bid = blockIdx.x;
  const int xcd = bid & 7;
  const int slot = bid >> 3;
  int c, b;
  if (slot < 64) {
    c = ((slot >> 5) << 3) + xcd;   // channels 0..15
    b = slot & 31;
  } else {
    const int widx = ((slot - 64) << 3) + xcd;  // 0..95
    c = 16 + (widx >> 5);           // channels 16..18
    b = widx & 31;
  }

  const int tid = threadIdx.x;
  const int w = tid >> 6;        // wave 0..7 == head index
  const int lane = tid & 63;
  const int quad = lane >> 4;
  const int l16 = lane & 15;

  extern __shared__ char smem[];
  unsigned short* sQ  = (unsigned short*)(smem);
  unsigned short* sK  = (unsigned short*)(smem + 16896);
  unsigned short* sVT = (unsigned short*)(smem + 33792);
  unsigned short* sX  = (unsigned short*)(smem + 54272);
  unsigned short* sP  = (unsigned short*)(smem + 54272) + w * (32 * 40);

  const float scale = 0.17677669529663687f;  // 1/sqrt(32)
  const floatx4 fzero = {0.f, 0.f, 0.f, 0.f};

  // ---------------- Phase 1: Q = xq @ wq^T + bq (scaled) -> sQ bf16 [32][264]
  {
    const int eh0 = w * 32;
#pragma unroll
    for (int mt = 0; mt < 2; ++mt) {
      const int xrow = b * NPAD + c * CC + mt * 16 + l16;  // zero-padded rows
      bf16x8 a8[8];
#pragma unroll
      for (int k = 0; k < 8; ++k)
        a8[k] = *(const bf16x8*)&xbf[xrow * DIM + k * 32 + quad * 8];
#pragma unroll
      for (int nt2 = 0; nt2 < 2; ++nt2) {
        const int e0 = eh0 + nt2 * 16;
        floatx4 acc = fzero;
#pragma unroll
        for (int k = 0; k < 8; ++k) {
          bf16x8 b8 = *(const bf16x8*)&wibf[(c * 768 + e0 + l16) * DIM + k * 32 + quad * 8];
          acc = __builtin_amdgcn_mfma_f32_16x16x32_bf16(a8[k], b8, acc, 0, 0, 0);
        }
        const float bias = b_in[c * 768 + e0 + l16];
#pragma unroll
        for (int r = 0; r < 4; ++r)
          sQ[(mt * 16 + quad * 4 + r) * 264 + e0 + l16] = f2bf((acc[r] + bias) * scale);
      }
    }
  }

  // attention running state (per wave-head; rows q = mt*16 + quad*4 + r)
  floatx4 o_acc[2][2];
  float m_run[2][4], l_run[2][4];
#pragma unroll
  for (int mt = 0; mt < 2; ++mt) {
#pragma unroll
    for (int nt2 = 0; nt2 < 2; ++nt2) o_acc[mt][nt2] = fzero;
#pragma unroll
    for (int r = 0; r < 4; ++r) { m_run[mt][r] = -1e30f; l_run[mt][r] = 0.f; }
  }
  const int eh = w * 32;

  for (int t = 0; t < NTILES; ++t) {
    const int t0 = t * TKEY;
    __syncthreads();  // protect sX(=sP) + sK/sVT reuse from previous tile

    // stage x tile [32][264 padded] bf16
#pragma unroll
    for (int it = 0; it < 2; ++it) {
      const int cc2 = tid + it * 512;
      const int row = cc2 >> 5;
      const int col = (cc2 & 31) * 8;
      *(bf16x8*)&sX[row * 264 + col] = *(const bf16x8*)&xbf[(b * NPAD + t0 + row) * DIM + col];
    }
    __syncthreads();

    // ---------------- KV^T projection: rows e' = w*64..w*64+63 of [wk;wv]
    {
      floatx4 acc[4][2];
#pragma unroll
      for (int m4 = 0; m4 < 4; ++m4)
#pragma unroll
        for (int n4 = 0; n4 < 2; ++n4) acc[m4][n4] = fzero;

      const int wrow0 = c * 768 + 256 + w * 64;
      bf16x8 abuf[2][4];
#pragma unroll
      for (int m4 = 0; m4 < 4; ++m4)
        abuf[0][m4] = *(const bf16x8*)&wibf[(wrow0 + m4 * 16 + l16) * DIM + quad * 8];
#pragma unroll
      for (int k = 0; k < 8; ++k) {
        if (k < 7) {
#pragma unroll
          for (int m4 = 0; m4 < 4; ++m4)
            abuf[(k + 1) & 1][m4] =
                *(const bf16x8*)&wibf[(wrow0 + m4 * 16 + l16) * DIM + (k + 1) * 32 + quad * 8];
        }
        bf16x8 bfr[2];
#pragma unroll
        for (int n4 = 0; n4 < 2; ++n4)
          bfr[n4] = *(const bf16x8*)&sX[(n4 * 16 + l16) * 264 + k * 32 + quad * 8];
#pragma unroll
        for (int m4 = 0; m4 < 4; ++m4)
#pragma unroll
          for (int n4 = 0; n4 < 2; ++n4)
            acc[m4][n4] = __builtin_amdgcn_mfma_f32_16x16x32_bf16(abuf[k & 1][m4], bfr[n4],
                                                                  acc[m4][n4], 0, 0, 0);
      }
      // epilogue: +bias, cvt bf16, store K [key][e] / V^T [e][key]
#pragma unroll
      for (int m4 = 0; m4 < 4; ++m4) {
        const float4 bv = *(const float4*)&b_in[c * 768 + 256 + w * 64 + m4 * 16 + quad * 4];
        const float ba[4] = {bv.x, bv.y, bv.z, bv.w};
#pragma unroll
        for (int n4 = 0; n4 < 2; ++n4) {
          const int key = n4 * 16 + l16;
          if (w < 4) {
            const int e0 = w * 64 + m4 * 16 + quad * 4;
            ushort4 pk;
            pk.x = f2bf(acc[m4][n4][0] + ba[0]);
            pk.y = f2bf(acc[m4][n4][1] + ba[1]);
            pk.z = f2bf(acc[m4][n4][2] + ba[2]);
            pk.w = f2bf(acc[m4][n4][3] + ba[3]);
            *(ushort4*)&sK[key * 264 + e0] = pk;
          } else {
            const int e0 = (w - 4) * 64 + m4 * 16 + quad * 4;
#pragma unroll
            for (int r = 0; r < 4; ++r)
              sVT[(e0 + r) * 40 + key] = f2bf(acc[m4][n4][r] + ba[r]);
          }
        }
      }
    }
    __syncthreads();

    // ---------------- scores + mask + online softmax + P (head = w)
    {
#pragma unroll
      for (int mt = 0; mt < 2; ++mt) {
        const bf16x8 aq = *(const bf16x8*)&sQ[(mt * 16 + l16) * 264 + eh + quad * 8];
        floatx4 sc[2];
#pragma unroll
        for (int n4 = 0; n4 < 2; ++n4) {
          const bf16x8 bk = *(const bf16x8*)&sK[(n4 * 16 + l16) * 264 + eh + quad * 8];
          sc[n4] = __builtin_amdgcn_mfma_f32_16x16x32_bf16(aq, bk, fzero, 0, 0, 0);
        }
        float rowm[4] = {-1e30f, -1e30f, -1e30f, -1e30f};
#pragma unroll
        for (int n4 = 0; n4 < 2; ++n4) {
          const int kabs = t0 + n4 * 16 + l16;
          const unsigned ki = ((unsigned)kabs * 110377u) >> 21;  // kabs/19 for kabs<=383
          const unsigned kj = (unsigned)kabs - ki * 19u;
#pragma unroll
          for (int r = 0; r < 4; ++r) {
            const unsigned j = (unsigned)(mt * 16 + quad * 4 + r);
            const bool ok = (kabs < NPOS) &&
                            (ki == (unsigned)c || kj == (unsigned)c || ki == j || kj == j);
            const float v = ok ? sc[n4][r] : -1e30f;
            sc[n4][r] = v;
            rowm[r] = fmaxf(rowm[r], v);
          }
        }
#pragma unroll
        for (int r = 0; r < 4; ++r) {
#pragma unroll
          for (int m = 1; m < 16; m <<= 1) rowm[r] = fmaxf(rowm[r], __shfl_xor(rowm[r], m));
        }
        float alpha[4];
#pragma unroll
        for (int r = 0; r < 4; ++r) {
          const float mnew = fmaxf(m_run[mt][r], rowm[r]);
          alpha[r] = __expf(m_run[mt][r] - mnew);
          m_run[mt][r] = mnew;
          l_run[mt][r] *= alpha[r];
        }
        float rs[4] = {0.f, 0.f, 0.f, 0.f};
#pragma unroll
        for (int n4 = 0; n4 < 2; ++n4) {
#pragma unroll
          for (int r = 0; r < 4; ++r) {
            const float p = __expf(sc[n4][r] - m_run[mt][r]);
            rs[r] += p;
            sP[(mt * 16 + quad * 4 + r) * 40 + n4 * 16 + l16] = f2bf(p);
          }
        }
#pragma unroll
        for (int r = 0; r < 4; ++r) {
#pragma unroll
          for (int m = 1; m < 16; m <<= 1) rs[r] += __shfl_xor(rs[r], m);
          l_run[mt][r] += rs[r];
        }
#pragma unroll
        for (int nt2 = 0; nt2 < 2; ++nt2)
#pragma unroll
          for (int r = 0; r < 4; ++r) o_acc[mt][nt2][r] *= alpha[r];
      }
    }
    __syncthreads();

    // ---------------- PV: O += P @ V (head = w), single K=32 step
    {
      bf16x8 ap[2], bv8[2];
#pragma unroll
      for (int mt = 0; mt < 2; ++mt)
        ap[mt] = *(const bf16x8*)&sP[(mt * 16 + l16) * 40 + quad * 8];
#pragma unroll
      for (int nt2 = 0; nt2 < 2; ++nt2)
        bv8[nt2] = *(const bf16x8*)&sVT[(eh + nt2 * 16 + l16) * 40 + quad * 8];
#pragma unroll
      for (int mt = 0; mt < 2; ++mt)
#pragma unroll
        for (int nt2 = 0; nt2 < 2; ++nt2)
          o_acc[mt][nt2] =
              __builtin_amdgcn_mfma_f32_16x16x32_bf16(ap[mt], bv8[nt2], o_acc[mt][nt2], 0, 0, 0);
    }
  }  // tile loop

  // ---------------- finalize O -> sQ (as attn-out, bf16)
#pragma unroll
  for (int mt = 0; mt < 2; ++mt) {
    float invl[4];
#pragma unroll
    for (int r = 0; r < 4; ++r) invl[r] = 1.f / l_run[mt][r];
#pragma unroll
    for (int nt2 = 0; nt2 < 2; ++nt2)
#pragma unroll
      for (int r = 0; r < 4; ++r)
        sQ[(mt * 16 + quad * 4 + r) * 264 + eh + nt2 * 16 + l16] = f2bf(o_acc[mt][nt2][r] * invl[r]);
  }
  __syncthreads();

  // ---------------- GEMM1: proj = AO @ w_out^T + b_out -> sK (bf16)
#pragma unroll
  for (int mt = 0; mt < 2; ++mt) {
    bf16x8 a8[8];
#pragma unroll
    for (int k = 0; k < 8; ++k)
      a8[k] = *(const bf16x8*)&sQ[(mt * 16 + l16) * 264 + k * 32 + quad * 8];
#pragma unroll
    for (int nt2 = 0; nt2 < 2; ++nt2) {
      const int e0 = w * 32 + nt2 * 16;
      floatx4 acc = fzero;
#pragma unroll
      for (int k = 0; k < 8; ++k) {
        bf16x8 b8 = *(const bf16x8*)&wobf[(c * 256 + e0 + l16) * DIM + k * 32 + quad * 8];
        acc = __builtin_amdgcn_mfma_f32_16x16x32_bf16(a8[k], b8, acc, 0, 0, 0);
      }
      const float bias = b_out[c * 256 + e0 + l16];
#pragma unroll
      for (int r = 0; r < 4; ++r)
        sK[(mt * 16 + quad * 4 + r) * 264 + e0 + l16] = f2bf(acc[r] + bias);
    }
  }
  __syncthreads();

  // ---------------- GEMM2: out = proj @ w_fuse^T + b_fuse + x
#pragma unroll
  for (int mt = 0; mt < 2; ++mt) {
    bf16x8 a8[8];
#pragma unroll
    for (int k = 0; k < 8; ++k)
      a8[k] = *(const bf16x8*)&sK[(mt * 16 + l16) * 264 + k * 32 + quad * 8];
#pragma unroll
    for (int nt2 = 0; nt2 < 2; ++nt2) {
      const int e0 = w * 32 + nt2 * 16;
      floatx4 acc = fzero;
#pragma unroll
      for (int k = 0; k < 8; ++k) {
        bf16x8 b8 = *(const bf16x8*)&wfbf[(e0 + l16) * DIM + k * 32 + quad * 8];
        acc = __builtin_amdgcn_mfma_f32_16x16x32_bf16(a8[k], b8, acc, 0, 0, 0);
      }
      const float bfu = b_fuse[e0 + l16];
#pragma unroll
      for (int r = 0; r < 4; ++r) {
        const int row = mt * 16 + quad * 4 + r;
        if (row < CC) {
          const int gp = (b * NPOS + c * CC + row) * DIM + e0 + l16;
          out[gp] = acc[r] + bfu + xf[gp];
        }
      }
    }
  }
}

extern "C" void kernel_launch(void* const* d_in, const int* in_sizes, int n_in,
                              void* d_out, int out_size, void* d_ws, size_t ws_size,
                              hipStream_t stream) {
  const float* x      = (const float*)d_in[0];
  const float* w_in   = (const float*)d_in[1];
  const float* b_in   = (const float*)d_in[2];
  const float* w_out  = (const float*)d_in[3];
  const float* b_out  = (const float*)d_in[4];
  const float* w_fuse = (const float*)d_in[5];
  const float* b_fuse = (const float*)d_in[6];
  float* out = (float*)d_out;

  if (ws_size < (size_t)16384000) return;  // need 15.6 MB of bf16 scratch

  unsigned short* ws = (unsigned short*)d_ws;
  unsigned short* x_bf  = ws;              // 32*384*256   = 3,145,728
  unsigned short* wi_bf = ws + 3145728;    // 19*768*256   = 3,735,552
  unsigned short* wo_bf = ws + 6881280;    // 19*256*256   = 1,245,184
  unsigned short* wf_bf = ws + 8126464;    // 256*256      = 65,536

  conv_all_kernel<<<8000, 256, 0, stream>>>(x, w_in, w_out, w_fuse, ws);

  (void)hipFuncSetAttribute((const void*)cgca_kernel,
                            hipFuncAttributeMaxDynamicSharedMemorySize, LDS_BYTES);
  cgca_kernel<<<608, 512, LDS_BYTES, stream>>>(x, b_in, b_out, b_fuse, x_bf, wi_bf,
                                               wo_bf, wf_bf, out);
}